// Round 4
// baseline (10829.424 us; speedup 1.0000x reference)
//
#include <hip/hip_runtime.h>
#include <hip/hip_fp16.h>

// B=64, T=512, D=96, H=256
constexpr int Tt = 512, Dd = 96, Hh = 256;
constexpr int NS0 = 16;   // h0 ring depth
constexpr int NS1 = 16;   // h1 ring depth
constexpr int NSP = 8;    // P0 ring depth
typedef unsigned long long u64;

// workspace layout
constexpr size_t OFF_H0  = 0;                                  // 32 grp * 16*1024 u64 = 4MB
constexpr size_t OFF_P0  = (size_t)4 << 20;                    // 32 grp * 8*4096 u64 = 8MB
constexpr size_t OFF_H1  = (size_t)12 << 20;                   // 32 grp * 16*1024 u64 = 4MB
constexpr size_t OFF_FLG = (size_t)20 << 20;                   // 32 grp * 16 flags * 128B = 64KB
constexpr size_t OFF_W16 = ((size_t)20 << 20) + ((size_t)64 << 10);

// packed fp16-pair weight slices (unsigned units), chunk-tiled transpose per slice
constexpr size_t sG_p0 = (size_t)384 * 48,  oG_p0 = 0;
constexpr size_t sG_r0 = (size_t)384 * 128, oG_r0 = oG_p0 + 2 * sG_p0;
constexpr size_t sG_r1 = (size_t)192 * 256, oG_r1 = oG_r0 + 2 * sG_r0;
constexpr size_t sL_p0 = (size_t)512 * 48,  oL_p0 = oG_r1 + 4 * sG_r1;
constexpr size_t sL_r0 = (size_t)512 * 128, oL_r0 = oL_p0 + 2 * sL_p0;
constexpr size_t sL_r1 = (size_t)256 * 256, oL_r1 = oL_r0 + 2 * sL_r0;

__device__ __forceinline__ float sigf(float v) { return 1.0f / (1.0f + __expf(-v)); }
__device__ __forceinline__ u64 agld(const u64* p) {
    return __hip_atomic_load(p, __ATOMIC_RELAXED, __HIP_MEMORY_SCOPE_AGENT);
}
__device__ __forceinline__ int agldi(const int* p) {
    return __hip_atomic_load(p, __ATOMIC_ACQUIRE, __HIP_MEMORY_SCOPE_AGENT);
}
__device__ __forceinline__ void agst(u64* p, u64 v) {
    __hip_atomic_store(p, v, __ATOMIC_RELAXED, __HIP_MEMORY_SCOPE_AGENT);
}
__device__ __forceinline__ void xrel(int* p, int v) {
    __hip_atomic_exchange(p, v, __ATOMIC_RELEASE, __HIP_MEMORY_SCOPE_AGENT);
}
__device__ __forceinline__ float pollF(const u64* p, unsigned want) {
    u64 v = agld(p);
    while ((unsigned)v != want) v = agld(p);
    return __uint_as_float((unsigned)(v >> 32));
}
__device__ __forceinline__ void waitFlags(const int* flg, int fid0, int n, int need) {
    for (;;) {
        int m = 0x7fffffff;
        for (int i = 0; i < n; ++i) m = min(m, agldi(flg + (fid0 + i) * 32));
        if (m >= need) break;
        __builtin_amdgcn_s_sleep(1);
    }
}

// fp16x2 dot into f32 accumulator (v_dot2_f32_f16)
__device__ __forceinline__ float dot2f(unsigned w, unsigned a, float acc) {
#if __has_builtin(__builtin_amdgcn_fdot2)
    typedef _Float16 h2v __attribute__((ext_vector_type(2)));
    h2v wh, ah;
    __builtin_memcpy(&wh, &w, 4);
    __builtin_memcpy(&ah, &a, 4);
    return __builtin_amdgcn_fdot2(wh, ah, acc, false);
#else
    const float2 wf = __half22float2(*(const __half2*)&w);
    const float2 af = __half22float2(*(const __half2*)&a);
    acc = fmaf(wf.x, af.x, acc);
    return fmaf(wf.y, af.y, acc);
#endif
}

// A operand LDS layout: uint4 per kp; .x/.y/.z/.w = batch rows 0..3, each half2
__device__ __forceinline__ int hidx(int k, int r) {
    return (k >> 1) * 8 + r * 2 + (k & 1);
}

// one 4-kp chunk of one weight column against 4 batch rows (16 dot2)
__device__ __forceinline__ void fmaC(const uint4 w, const uint4* __restrict__ A4,
                                     int kpb, float4& a) {
    const uint4 a0 = A4[kpb + 0], a1 = A4[kpb + 1], a2 = A4[kpb + 2], a3 = A4[kpb + 3];
    a.x = dot2f(w.x, a0.x, a.x); a.y = dot2f(w.x, a0.y, a.y);
    a.z = dot2f(w.x, a0.z, a.z); a.w = dot2f(w.x, a0.w, a.w);
    a.x = dot2f(w.y, a1.x, a.x); a.y = dot2f(w.y, a1.y, a.y);
    a.z = dot2f(w.y, a1.z, a.z); a.w = dot2f(w.y, a1.w, a.w);
    a.x = dot2f(w.z, a2.x, a.x); a.y = dot2f(w.z, a2.y, a.y);
    a.z = dot2f(w.z, a2.z, a.z); a.w = dot2f(w.z, a2.w, a.w);
    a.x = dot2f(w.w, a3.x, a.x); a.y = dot2f(w.w, a3.y, a.y);
    a.z = dot2f(w.w, a3.z, a.z); a.w = dot2f(w.w, a3.w, a.w);
}

// 2 columns (c, 256+c), depth-2 over chunks
__device__ __forceinline__ void gemmG2(const uint4* __restrict__ Mc, int NC,
                                       const uint4* __restrict__ A4,
                                       int kp0, int n4, float4& X0, float4& X1) {
    int cb = kp0 >> 2;
    uint4 p0 = Mc[(size_t)cb * NC], p1 = Mc[(size_t)cb * NC + 256];
    for (int i = 0; i < n4; ++i) {
        uint4 q0 = p0, q1 = p1;
        if (i + 1 < n4) {
            q0 = Mc[(size_t)(cb + 1) * NC];
            q1 = Mc[(size_t)(cb + 1) * NC + 256];
        }
        fmaC(p0, A4, cb * 4, X0);
        fmaC(p1, A4, cb * 4, X1);
        p0 = q0; p1 = q1; ++cb;
    }
}

// 1 column, depth-4 over chunks (n4 % 4 == 0)
__device__ __forceinline__ void gemmG1(const uint4* __restrict__ Mc, int NC,
                                       const uint4* __restrict__ A4,
                                       int kp0, int n4, float4& X0) {
    int cb = kp0 >> 2;
    uint4 w0 = Mc[(size_t)(cb + 0) * NC], w1 = Mc[(size_t)(cb + 1) * NC],
          w2 = Mc[(size_t)(cb + 2) * NC], w3 = Mc[(size_t)(cb + 3) * NC];
    for (int i = 0; i < n4; i += 4) {
        uint4 n0 = w0, n1 = w1, n2 = w2, n3 = w3;
        if (i + 4 < n4) {
            n0 = Mc[(size_t)(cb + 4) * NC]; n1 = Mc[(size_t)(cb + 5) * NC];
            n2 = Mc[(size_t)(cb + 6) * NC]; n3 = Mc[(size_t)(cb + 7) * NC];
        }
        fmaC(w0, A4, (cb + 0) * 4, X0);
        fmaC(w1, A4, (cb + 1) * 4, X0);
        fmaC(w2, A4, (cb + 2) * 4, X0);
        fmaC(w3, A4, (cb + 3) * 4, X0);
        w0 = n0; w1 = n1; w2 = n2; w3 = n3; cb += 4;
    }
}

// f32 weights -> fp16-pair chunk-tiled slice.
// packed col j: gate = j>>NUs, unit = u0 + (j & (NU-1)); src col = gate*256 + unit.
// dst[((dkp>>2)*NC + j)*4 + (dkp&3)], dkp = kp + kOff.
__global__ void cvt_slice(const float* __restrict__ src, unsigned* __restrict__ dst,
                          int srcN, int kpTot, int NC, int NUs, int u0, int kOff) {
    const int i = blockIdx.x * 256 + threadIdx.x;
    const int total = kpTot * NC;
    if (i >= total) return;
    const int kp = i / NC, j = i - kp * NC;
    const int g = j >> NUs, u = j & ((1 << NUs) - 1);
    const int scol = g * 256 + u0 + u;
    const __half2 h = __floats2half2_rn(src[(size_t)(2 * kp) * srcN + scol],
                                        src[(size_t)(2 * kp + 1) * srcN + scol]);
    const int dkp = kp + kOff;
    dst[((size_t)(dkp >> 2) * NC + j) * 4 + (dkp & 3)] = *(const unsigned*)&h;
}

// 256 blocks: bx = chain*8 + role + 16*rg.
// roles: 0,1 = p0 sub (x@W0 halves); 2,3 = r0 sub (U0 halves + h0 update);
//        4..7 = r1 sub (fused [W1|U1]@[h0;h1'] quarters + h1 update + head)
// flags per group: 0,1: P0 consumed by r0a/b; 2..7: h0 consumed by r0a,r0b,r1a-d;
//                  8..11: h1 consumed by r1a-d. value = consumed-count.
__global__ void __launch_bounds__(512, 1)
rnn_persist(const float* __restrict__ x, const int* __restrict__ lengths,
            const float* __restrict__ gbi0, const float* __restrict__ gbr0,
            const float* __restrict__ gbi1, const float* __restrict__ gbr1,
            const float* __restrict__ lb0, const float* __restrict__ lb1,
            const float* __restrict__ outW, const float* __restrict__ outb,
            float* __restrict__ out, char* __restrict__ wsb)
{
    const int tid = threadIdx.x;
    const int c   = tid & 255;
    const int grp = tid >> 8;                    // 0/1: K halves
    const int bx  = blockIdx.x;
    const int role  = bx & 7;
    const int chain = (bx >> 3) & 1;
    const int rg    = bx >> 4;
    const int rowbase = rg * 4;
    const int kind = (role < 2) ? 0 : (role < 4) ? 1 : 2;
    const int sub  = (kind == 0) ? role : (kind == 1) ? role - 2 : role - 4;

    const int NG  = chain ? 4 : 3;
    const int GAH = NG * 256;

    const int grpid = chain * 16 + rg;
    u64* h0ring = (u64*)(wsb + OFF_H0) + (size_t)grpid * (NS0 * 1024);
    u64* p0ring = (u64*)(wsb + OFF_P0) + (size_t)grpid * (NSP * 4096);
    u64* h1ring = (u64*)(wsb + OFF_H1) + (size_t)grpid * (NS1 * 1024);
    int* flg    = (int*)(wsb + OFF_FLG) + grpid * (16 * 32);

    const unsigned* W16 = (const unsigned*)(wsb + OFF_W16);
    size_t woff; int NC, KPh;
    if (chain == 0) {
        if (kind == 0)      { woff = oG_p0 + (size_t)sub * sG_p0; NC = 384; KPh = 24; }
        else if (kind == 1) { woff = oG_r0 + (size_t)sub * sG_r0; NC = 384; KPh = 64; }
        else                { woff = oG_r1 + (size_t)sub * sG_r1; NC = 192; KPh = 128; }
    } else {
        if (kind == 0)      { woff = oL_p0 + (size_t)sub * sL_p0; NC = 512; KPh = 24; }
        else if (kind == 1) { woff = oL_r0 + (size_t)sub * sL_r0; NC = 512; KPh = 64; }
        else                { woff = oL_r1 + (size_t)sub * sL_r1; NC = 256; KPh = 128; }
    }
    const uint4* Mc = (const uint4*)(W16 + woff) + c;
    const int kp0 = grp * KPh;
    const int n4  = KPh >> 2;

    __shared__ __align__(16) unsigned sAh[1024];   // 256 kp (A operand)
    __shared__ float sG[8 * 512];                  // [grp][row][col<=512]
    __half* sAhh = (__half*)sAh;
    const uint4* A4 = (const uint4*)sAh;

    const int u0 = sub * 128;                      // kind 0/1 unit base
    const int q0 = sub * 64;                       // kind 2 unit base

    // p0 publish precompute
    int ringoff[4]; int sgi[4]; float biasv[4];
    if (kind == 0) {
        const float* bsrc = chain ? lb0 : gbi0;
        #pragma unroll
        for (int i = 0; i < 4; ++i) {
            if (i < NG) {
                const int e = tid + i * 512;
                const int r = e / NC, j = e - r * NC;
                const int g = j >> 7, uL = j & 127;
                ringoff[i] = r * GAH + g * 256 + u0 + uL;
                biasv[i]   = bsrc[g * 256 + u0 + uL];
                sgi[i]     = r * 512 + j;
            } else { ringoff[i] = 0; biasv[i] = 0.0f; sgi[i] = 0; }
        }
    }
    // r0 ownership: (row, unit) = (tid>>7, tid&127); r1: tid<256, (tid>>6, tid&63)
    const int rr1 = tid >> 7, uu1 = tid & 127;
    const int rr2 = (tid >> 6) & 3, uu2 = tid & 63;
    float br_[4] = {0, 0, 0, 0};
    if (kind == 1 && chain == 0)
        for (int g = 0; g < 3; ++g) br_[g] = gbr0[g * 256 + u0 + uu1];
    float biW[4] = {0, 0, 0, 0}, brU[4] = {0, 0, 0, 0}, ow = 0.0f;
    if (kind == 2 && tid < 256) {
        if (chain == 0) {
            for (int g = 0; g < 3; ++g) {
                biW[g] = gbi1[g * 256 + q0 + uu2];
                brU[g] = gbr1[g * 256 + q0 + uu2];
            }
        } else {
            for (int g = 0; g < 4; ++g) biW[g] = lb1[g * 256 + q0 + uu2];
        }
        ow = outW[chain * Hh + q0 + uu2];
    }
    int lenR = Tt + 1;
    if (kind == 1) lenR = lengths[rowbase + rr1];
    if (kind == 2 && tid < 256) lenR = lengths[rowbase + rr2];
    const float outb0 = outb[0];
    float hprev = 0.0f, creg = 0.0f;

    for (int i = tid; i < 1024; i += 512) sAh[i] = 0;   // h(-1) = 0, x region = 0
    __syncthreads();

    for (int t = 0; t < Tt; ++t) {
        // ================= phase 1: inputs =================
        if (kind == 0) {
            if (t >= NSP) {
                if (tid == 0) waitFlags(flg, sub, 1, t - NSP + 1);
                __syncthreads();
            }
            if (tid < 4 * Dd) {
                const int r = tid / Dd, k = tid - r * Dd;
                sAhh[hidx(k, r)] =
                    __float2half(x[((size_t)(rowbase + r) * Tt + t) * Dd + k]);
            }
        } else if (kind == 1) {
            if (t > 0) {   // peer half of h0(t-1), tag t
                const u64* base = h0ring + (size_t)((t - 1) & (NS0 - 1)) * 1024;
                const int pu0 = 128 - u0;
                const float v = pollF(base + rr1 * 256 + pu0 + uu1, (unsigned)t);
                sAhh[hidx(pu0 + uu1, rr1)] = __float2half(v);
            }
        } else {
            // h0(t), tag t+1 -> A kp [0,128)
            const u64* b0 = h0ring + (size_t)(t & (NS0 - 1)) * 1024;
            #pragma unroll
            for (int i = 0; i < 2; ++i) {
                const int e = tid + i * 512, un = e & 255, r = e >> 8;
                sAhh[hidx(un, r)] =
                    __float2half(pollF(b0 + r * 256 + un, (unsigned)(t + 1)));
            }
            if (t > 0) {   // h1(t-1), tag t -> A kp [128,256)
                const u64* b1 = h1ring + (size_t)((t - 1) & (NS1 - 1)) * 1024;
                #pragma unroll
                for (int i = 0; i < 2; ++i) {
                    const int e = tid + i * 512, un = e & 255, r = e >> 8;
                    sAhh[hidx(256 + un, r)] =
                        __float2half(pollF(b1 + r * 256 + un, (unsigned)t));
                }
            }
        }
        __syncthreads();

        // ================= phase 2: GEMM =================
        if (kind <= 1) {
            float4 X0 = {0, 0, 0, 0}, X1 = {0, 0, 0, 0};
            gemmG2(Mc, NC, A4, kp0, n4, X0, X1);
            const int b = grp * 2048;
            sG[b + 0 * 512 + c] = X0.x; sG[b + 1 * 512 + c] = X0.y;
            sG[b + 2 * 512 + c] = X0.z; sG[b + 3 * 512 + c] = X0.w;
            if (c + 256 < NC) {
                sG[b + 0 * 512 + 256 + c] = X1.x; sG[b + 1 * 512 + 256 + c] = X1.y;
                sG[b + 2 * 512 + 256 + c] = X1.z; sG[b + 3 * 512 + 256 + c] = X1.w;
            }
        } else {
            float4 X0 = {0, 0, 0, 0};
            gemmG1(Mc, NC, A4, kp0, n4, X0);
            const int b = grp * 2048;
            sG[b + 0 * 512 + c] = X0.x; sG[b + 1 * 512 + c] = X0.y;
            sG[b + 2 * 512 + c] = X0.z; sG[b + 3 * 512 + c] = X0.w;
        }
        __syncthreads();

        // ================= phase 3: publish / update =================
        if (kind == 0) {
            u64* slot = p0ring + (size_t)(t & (NSP - 1)) * 4096;
            #pragma unroll
            for (int i = 0; i < 4; ++i) {
                if (i < NG) {
                    const float v = sG[sgi[i]] + sG[2048 + sgi[i]] + biasv[i];
                    agst(slot + ringoff[i],
                         ((u64)__float_as_uint(v) << 32) | (unsigned)(t + 1));
                }
            }
        } else if (kind == 1) {
            const u64* pslot = p0ring + (size_t)(t & (NSP - 1)) * 4096;
            float P[4] = {0, 0, 0, 0}, Q[4] = {0, 0, 0, 0};
            #pragma unroll
            for (int g = 0; g < 4; ++g) {
                if (g < NG) {
                    P[g] = pollF(pslot + rr1 * GAH + g * 256 + u0 + uu1,
                                 (unsigned)(t + 1));
                    const int j = g * 128 + uu1;
                    Q[g] = sG[rr1 * 512 + j] + sG[2048 + rr1 * 512 + j];
                }
            }
            const float hold = hprev;
            float hn;
            if (chain == 0) {
                const float z  = sigf(P[0] + Q[0] + br_[0]);
                const float r_ = sigf(P[1] + Q[1] + br_[1]);
                const float hh = tanhf(P[2] + r_ * (Q[2] + br_[2]));
                hn = z * hold + (1.0f - z) * hh;
                if (t >= lenR) hn = hold;
            } else {
                float cn = sigf(P[1] + Q[1]) * creg
                         + sigf(P[0] + Q[0]) * tanhf(P[2] + Q[2]);
                hn = sigf(P[3] + Q[3]) * tanhf(cn);
                if (t >= lenR) { hn = hold; cn = creg; }
                creg = cn;
            }
            hprev = hn;
            if (t >= NS0) {
                if (tid == 0) waitFlags(flg, 2, 6, t - NS0 + 1);
                __syncthreads();
            }
            agst(h0ring + (size_t)(t & (NS0 - 1)) * 1024 + rr1 * 256 + u0 + uu1,
                 ((u64)__float_as_uint(hn) << 32) | (unsigned)(t + 1));
            sAhh[hidx(u0 + uu1, rr1)] = __float2half(hn);   // own half for next GEMM
        } else {
            const bool act = tid < 256;
            float hn = 0.0f;
            if (act) {
                float W[4] = {0, 0, 0, 0}, U[4] = {0, 0, 0, 0};
                #pragma unroll
                for (int g = 0; g < 4; ++g) {
                    if (g < NG) {
                        const int j = g * 64 + uu2;
                        W[g] = sG[rr2 * 512 + j] + biW[g];
                        U[g] = sG[2048 + rr2 * 512 + j] + brU[g];
                    }
                }
                const float hold = hprev;
                if (chain == 0) {
                    const float z  = sigf(W[0] + U[0]);
                    const float r_ = sigf(W[1] + U[1]);
                    const float hh = tanhf(W[2] + r_ * U[2]);
                    hn = z * hold + (1.0f - z) * hh;
                    if (t >= lenR) hn = hold;
                } else {
                    float cn = sigf(W[1] + U[1]) * creg
                             + sigf(W[0] + U[0]) * tanhf(W[2] + U[2]);
                    hn = sigf(W[3] + U[3]) * tanhf(cn);
                    if (t >= lenR) { hn = hold; cn = creg; }
                    creg = cn;
                }
                hprev = hn;
            }
            if (t >= NS1) {
                if (tid == 0) waitFlags(flg, 8, 4, t - NS1 + 1);
                __syncthreads();
            }
            if (act) {
                agst(h1ring + (size_t)(t & (NS1 - 1)) * 1024 + rr2 * 256 + q0 + uu2,
                     ((u64)__float_as_uint(hn) << 32) | (unsigned)(t + 1));
                float vh = hn * ow;
                #pragma unroll
                for (int o = 32; o > 0; o >>= 1) vh += __shfl_down(vh, o);
                if ((tid & 63) == 0)
                    atomicAdd(&out[(size_t)(rowbase + rr2) * Tt + t],
                              vh + ((chain == 1 && sub == 0) ? outb0 : 0.0f));
            }
        }
        __syncthreads();   // sAh/sG safe for next iteration
        if (tid == 0) {
            if (kind == 1) {
                xrel(flg + (0 + sub) * 32, t + 1);   // P0 consumed through t
                xrel(flg + (2 + sub) * 32, t);       // h0 consumed through t-1
            } else if (kind == 2) {
                xrel(flg + (4 + sub) * 32, t + 1);   // h0 consumed through t
                xrel(flg + (8 + sub) * 32, t);       // h1 consumed through t-1
            }
        }
    }
}

extern "C" void kernel_launch(void* const* d_in, const int* in_sizes, int n_in,
                              void* d_out, int out_size, void* d_ws, size_t ws_size,
                              hipStream_t stream) {
    const float* x       = (const float*)d_in[0];
    const int*   lengths = (const int*)d_in[1];
    const float* gW0  = (const float*)d_in[2];
    const float* gU0  = (const float*)d_in[3];
    const float* gbi0 = (const float*)d_in[4];
    const float* gbr0 = (const float*)d_in[5];
    const float* gW1  = (const float*)d_in[6];
    const float* gU1  = (const float*)d_in[7];
    const float* gbi1 = (const float*)d_in[8];
    const float* gbr1 = (const float*)d_in[9];
    const float* lW0  = (const float*)d_in[10];
    const float* lU0  = (const float*)d_in[11];
    const float* lb0  = (const float*)d_in[12];
    const float* lW1  = (const float*)d_in[13];
    const float* lU1  = (const float*)d_in[14];
    const float* lb1  = (const float*)d_in[15];
    const float* outW = (const float*)d_in[16];
    const float* outb = (const float*)d_in[17];
    float* out = (float*)d_out;
    char* wsb  = (char*)d_ws;

    hipMemsetAsync(d_ws, 0, OFF_W16, stream);     // rings + flags reset
    hipMemsetAsync(d_out, 0, (size_t)out_size * sizeof(float), stream);

    unsigned* W16 = (unsigned*)(wsb + OFF_W16);
    struct CV { const float* s; size_t off; int srcN, kpTot, NC, NUs, u0, kOff; };
    CV cv[24]; int n = 0;
    for (int sub = 0; sub < 2; ++sub)
        cv[n++] = {gW0, oG_p0 + sub * sG_p0, 768, 48, 384, 7, sub * 128, 0};
    for (int sub = 0; sub < 2; ++sub)
        cv[n++] = {gU0, oG_r0 + sub * sG_r0, 768, 128, 384, 7, sub * 128, 0};
    for (int sub = 0; sub < 4; ++sub) {
        cv[n++] = {gW1, oG_r1 + sub * sG_r1, 768, 128, 192, 6, sub * 64, 0};
        cv[n++] = {gU1, oG_r1 + sub * sG_r1, 768, 128, 192, 6, sub * 64, 128};
    }
    for (int sub = 0; sub < 2; ++sub)
        cv[n++] = {lW0, oL_p0 + sub * sL_p0, 1024, 48, 512, 7, sub * 128, 0};
    for (int sub = 0; sub < 2; ++sub)
        cv[n++] = {lU0, oL_r0 + sub * sL_r0, 1024, 128, 512, 7, sub * 128, 0};
    for (int sub = 0; sub < 4; ++sub) {
        cv[n++] = {lW1, oL_r1 + sub * sL_r1, 1024, 128, 256, 6, sub * 64, 0};
        cv[n++] = {lU1, oL_r1 + sub * sL_r1, 1024, 128, 256, 6, sub * 64, 128};
    }
    for (int i = 0; i < 24; ++i) {
        const int tot = cv[i].kpTot * cv[i].NC;
        cvt_slice<<<(tot + 255) / 256, 256, 0, stream>>>(
            cv[i].s, W16 + cv[i].off, cv[i].srcN, cv[i].kpTot, cv[i].NC,
            cv[i].NUs, cv[i].u0, cv[i].kOff);
    }

    rnn_persist<<<dim3(256), dim3(512), 0, stream>>>(
        x, lengths, gbi0, gbr0, gbi1, gbr1, lb0, lb1, outW, outb, out, wsb);
}